// Round 18
// baseline (88.730 us; speedup 1.0000x reference)
//
#include <hip/hip_runtime.h>

#define NCLS 81
#define BB 32
#define PP 24564
#define TT 20
#define BP_SEGS 8
#define BP_SEG 3072                       /* 8*3072 = 24576 >= 24564 */
#define KL_BLOCKS 1024                    /* 4 blocks/CU x 256 CU, exactly resident */
#define KL_ROWS 32                        /* rows per staged chunk */
#define KL_CHUNKS ((BB * PP) / KL_ROWS)   /* 786048/32 = 24564 exactly */
#define KL_F4 ((KL_ROWS * NCLS) / 4)      /* 648 float4 per chunk */

// async global->LDS DMA, 16B per lane; LDS dest = wave-uniform base + lane*16
#define GLOAD_LDS16(g, l)                                                  \
    __builtin_amdgcn_global_load_lds(                                      \
        (const __attribute__((address_space(1))) void*)(g),                \
        (__attribute__((address_space(3))) void*)(l), 16, 0, 0)

// Per-(b, prior-segment) block: 3 priors/thread in registers, loop 20 truths
// computing the EXACT f32 IoU quotient per (p,t).
//  (a) per-t argmax key (ov_bits<<32 | ~p) -> wave reduce -> 16-wave fold ->
//      atomicMax into bp_final[b*TT+t] (order-independent -> deterministic;
//      R12-proven: 5120 atomics over 640 addresses)
//  (b) per-prior best-truth key (ov_bits<<32 | 31-t) -> bovbt[b*PP+p]
__global__ __launch_bounds__(1024)
void k_bp(const float* __restrict__ priors,
          const float* __restrict__ targets,
          unsigned long long* __restrict__ bp_final,
          unsigned long long* __restrict__ bovbt)
{
    const int seg = blockIdx.x;   // 0..7
    const int b = blockIdx.y;

    __shared__ float trb[TT * 5];
    __shared__ unsigned long long wred[TT][16];
    if (threadIdx.x < TT * 5) trb[threadIdx.x] = targets[b * TT * 5 + threadIdx.x];
    __syncthreads();

    float X1[3], Y1[3], X2[3], Y2[3], pa[3];
    unsigned int pkey[3];
    bool ok[3];
    #pragma unroll
    for (int j = 0; j < 3; ++j) {
        int p = seg * BP_SEG + j * 1024 + threadIdx.x;
        ok[j] = p < PP;
        float4 pr = ok[j] ? ((const float4*)priors)[p] : make_float4(1.f, 1.f, 0.f, 0.f);
        float hw = __fmul_rn(pr.z, 0.5f), hh = __fmul_rn(pr.w, 0.5f);
        X1[j] = __fsub_rn(pr.x, hw); Y1[j] = __fsub_rn(pr.y, hh);
        X2[j] = __fadd_rn(pr.x, hw); Y2[j] = __fadd_rn(pr.y, hh);
        pa[j] = __fmul_rn(__fsub_rn(X2[j], X1[j]), __fsub_rn(Y2[j], Y1[j]));
        pkey[j] = 0xFFFFFFFFu - (unsigned)p;
    }

    const int wv = threadIdx.x >> 6;
    const int lane = threadIdx.x & 63;

    unsigned long long bkey[3] = {0ull, 0ull, 0ull};

    for (int t = 0; t < TT; ++t) {
        float tx1 = trb[t * 5 + 0], ty1 = trb[t * 5 + 1];
        float tx2 = trb[t * 5 + 2], ty2 = trb[t * 5 + 3];
        float ta = __fmul_rn(__fsub_rn(tx2, tx1), __fsub_rn(ty2, ty1));

        unsigned long long best = 0ull;
        #pragma unroll
        for (int j = 0; j < 3; ++j) {
            float lx = fmaxf(tx1, X1[j]), ly = fmaxf(ty1, Y1[j]);
            float rx = fminf(tx2, X2[j]), ry = fminf(ty2, Y2[j]);
            float w = fmaxf(__fsub_rn(rx, lx), 0.0f);
            float h = fmaxf(__fsub_rn(ry, ly), 0.0f);
            float inter = __fmul_rn(w, h);
            float denom = __fsub_rn(__fadd_rn(ta, pa[j]), inter);
            float ov = __fdiv_rn(inter, denom);   // exact numpy quotient bits
            unsigned long long ovhi = (unsigned long long)__float_as_uint(ov) << 32;
            unsigned long long key = ok[j] ? (ovhi | pkey[j]) : 0ull;
            if (key > best) best = key;
            unsigned long long rowk = ovhi | (unsigned long long)(31 - t);
            if (rowk > bkey[j]) bkey[j] = rowk;   // ties: smaller t (numpy first-max)
        }
        #pragma unroll
        for (int s = 32; s; s >>= 1) {
            unsigned long long o = __shfl_xor(best, s, 64);
            if (o > best) best = o;
        }
        if (lane == 0) wred[t][wv] = best;
    }

    #pragma unroll
    for (int j = 0; j < 3; ++j) {
        int p = seg * BP_SEG + j * 1024 + threadIdx.x;
        if (p < PP) bovbt[b * PP + p] = bkey[j];
    }

    __syncthreads();
    if (threadIdx.x < TT) {
        unsigned long long m = wred[threadIdx.x][0];
        #pragma unroll
        for (int w = 1; w < 16; ++w) if (wred[threadIdx.x][w] > m) m = wred[threadIdx.x][w];
        atomicMax(&bp_final[b * TT + threadIdx.x], m);
    }
}

// Streaming kernel: proven 32-row DMA double-buffer + 8-lane exp-sum skeleton.
// Per chunk the leader stores ONLY se (one LDS write); every 8 chunks a
// 256-thread lane-parallel burst does ALL tail logic: bovbt key + 20-entry
// forced scan (bpAll, loaded once) + thresholds + encode/SL1 + focal, with
// x[cc] re-read from conf (L2-hot: the row was DMA'd <=8 chunks = 332 KB ago).
__global__ __launch_bounds__(256, 4)
void k_stream(const float* __restrict__ conf,
              const float* __restrict__ loc,
              const float* __restrict__ priors,
              const float* __restrict__ targets,
              const unsigned long long* __restrict__ bp_final,
              const unsigned long long* __restrict__ bovbt,
              float* __restrict__ pl, float* __restrict__ pn, float* __restrict__ pc)
{
    __shared__ float buf[2][KL_ROWS * NCLS];    // 20736 B
    __shared__ float trbAll[BB * TT * 5];       // 12800 B
    __shared__ unsigned int bpAll[BB * TT];     // 2560 B
    __shared__ float seb[256];                  // 1024 B
    __shared__ int sidx[8];                     // 32 B
    __shared__ float red[256];                  // 1024 B  (total ~38.2 KB -> 4/CU)

    const int tid = threadIdx.x;
    const int w = tid >> 6;
    const int lane = tid & 63;
    const int rl = tid >> 3;       // local row 0..31
    const int k = tid & 7;         // 8-group position within row
    const float4* conf4 = (const float4*)conf;

    auto stage = [&](int c, int bi) {
        const float4* src = conf4 + (size_t)c * KL_F4;
        float4* dst = (float4*)buf[bi];
        #pragma unroll
        for (int j = 0; j < 2; ++j) {
            int idx = j * 256 + w * 64 + lane;
            GLOAD_LDS16(src + idx, dst + idx);
        }
        if (tid < KL_F4 - 512) {
            int idx = 512 + tid;
            GLOAD_LDS16(src + idx, dst + idx);
        }
    };

    for (int i = tid; i < BB * TT * 5; i += 256) trbAll[i] = targets[i];
    for (int i = tid; i < BB * TT; i += 256)
        bpAll[i] = 0xFFFFFFFFu - (unsigned)(bp_final[i] & 0xFFFFFFFFull);

    const int c0 = blockIdx.x;
    stage(c0, 0);
    __syncthreads();

    float accL = 0.0f, accN = 0.0f, accC = 0.0f;
    int cur = 0, na = 0;

    // 256-thread lane-parallel deferred tail over n staged chunks
    auto burst = [&](int n) {
        int span = tid >> 5;                    // 0..7
        if (span < n) {
            int r = sidx[span] * KL_ROWS + (tid & 31);
            int b = r / PP;
            int p = r - b * PP;
            const float* trb = &trbAll[b * TT * 5];
            const unsigned int* bpb = &bpAll[b * TT];

            unsigned long long rk = bovbt[r];   // coalesced, L2-hot
            int bt = 31 - (int)(rk & 31ull);
            float bov = __uint_as_float((unsigned)(rk >> 32));
            int ft = -1;
            #pragma unroll
            for (int t = 0; t < TT; ++t) {
                if (bpb[t] == (unsigned)p) ft = t;   // last t wins (numpy scatter)
            }
            if (ft >= 0) { bt = ft; bov = 2.0f; }
            int cc = (int)trb[bt * 5 + 4] + 1;
            if (bov < 0.5f) cc = -1;
            if (bov < 0.4f) cc = 0;

            if (cc > 0) {
                float4 pr = *(const float4*)(priors + p * 4);
                float mx1 = trb[bt * 5 + 0], my1 = trb[bt * 5 + 1];
                float mx2 = trb[bt * 5 + 2], my2 = trb[bt * 5 + 3];
                float cx = __fmul_rn(__fadd_rn(mx1, mx2), 0.5f);
                float cy = __fmul_rn(__fadd_rn(my1, my2), 0.5f);
                float gx = __fdiv_rn(__fsub_rn(cx, pr.x), __fmul_rn(0.1f, pr.z));
                float gy = __fdiv_rn(__fsub_rn(cy, pr.y), __fmul_rn(0.1f, pr.w));
                float gw = __fdiv_rn(logf(__fdiv_rn(__fsub_rn(mx2, mx1), pr.z)), 0.2f);
                float gh = __fdiv_rn(logf(__fdiv_rn(__fsub_rn(my2, my1), pr.w)), 0.2f);
                float4 ld = *(const float4*)(loc + (size_t)r * 4);
                float g0 = ld.x - gx, g1 = ld.y - gy, g2 = ld.z - gw, g3 = ld.w - gh;
                float a0 = fabsf(g0), a1 = fabsf(g1), a2 = fabsf(g2), a3 = fabsf(g3);
                accL += (a0 < 1.0f) ? 0.5f * g0 * g0 : (a0 - 0.5f);
                accL += (a1 < 1.0f) ? 0.5f * g1 * g1 : (a1 - 0.5f);
                accL += (a2 < 1.0f) ? 0.5f * g2 * g2 : (a2 - 0.5f);
                accL += (a3 < 1.0f) ? 0.5f * g3 * g3 : (a3 - 0.5f);
                accN += 1.0f;
            }
            if (cc >= 0) {
                float xt = conf[(size_t)r * NCLS + cc];   // L2-hot re-read
                float logpt = xt - __logf(seb[span * 32 + (tid & 31)]);
                float pt = __expf(logpt);
                float at = (cc > 0) ? 0.25f : 0.75f;
                float om = 1.0f - pt;
                accC -= at * om * om * logpt;
            }
        }
        __syncthreads();   // protect seb/sidx ring before reuse
    };

    for (int c = c0; c < KL_CHUNKS; c += KL_BLOCKS) {
        int cn = c + KL_BLOCKS;
        if (cn < KL_CHUNKS) stage(cn, cur ^ 1);

        // ---- exp-sum phase (8 threads/row) ----
        const float* row = buf[cur] + rl * NCLS;
        float se = 0.0f;
        #pragma unroll
        for (int i = 0; i < 10; ++i) se += __expf(row[k * 10 + i]);
        if (k == 0) se += __expf(row[80]);
        se += __shfl_xor(se, 1, 8);
        se += __shfl_xor(se, 2, 8);
        se += __shfl_xor(se, 4, 8);

        if (k == 0) seb[na * 32 + rl] = se;   // leader: ONE store, nothing else
        if (tid == 0) sidx[na] = c;
        __syncthreads();   // dbuf safety + seb/sidx visible
        ++na;
        if (na == 8) { burst(8); na = 0; }
        cur ^= 1;
    }
    if (na > 0) burst(na);

    // ---- block reduction ----
    red[tid] = accL;
    __syncthreads();
    for (int s = 128; s; s >>= 1) {
        if (tid < s) red[tid] += red[tid + s];
        __syncthreads();
    }
    if (tid == 0) pl[blockIdx.x] = red[0];
    __syncthreads();

    red[tid] = accN;
    __syncthreads();
    for (int s = 128; s; s >>= 1) {
        if (tid < s) red[tid] += red[tid + s];
        __syncthreads();
    }
    if (tid == 0) pn[blockIdx.x] = red[0];
    __syncthreads();

    red[tid] = accC;
    __syncthreads();
    for (int s = 128; s; s >>= 1) {
        if (tid < s) red[tid] += red[tid + s];
        __syncthreads();
    }
    if (tid == 0) pc[blockIdx.x] = red[0];
}

__global__ __launch_bounds__(256)
void k_final(const float* __restrict__ pl, const float* __restrict__ pn,
             const float* __restrict__ pc, float* __restrict__ out)
{
    __shared__ float sl[256], sc[256], sn[256];
    float L = 0.0f, C = 0.0f, N = 0.0f;
    for (int i = threadIdx.x; i < KL_BLOCKS; i += 256) {
        L += pl[i]; N += pn[i]; C += pc[i];
    }
    sl[threadIdx.x] = L; sc[threadIdx.x] = C; sn[threadIdx.x] = N;
    __syncthreads();
    for (int s = 128; s; s >>= 1) {
        if (threadIdx.x < s) {
            sl[threadIdx.x] += sl[threadIdx.x + s];
            sc[threadIdx.x] += sc[threadIdx.x + s];
            sn[threadIdx.x] += sn[threadIdx.x + s];
        }
        __syncthreads();
    }
    if (threadIdx.x == 0) {
        out[0] = sl[0] / sn[0];
        out[1] = sc[0] / sn[0];
    }
}

extern "C" void kernel_launch(void* const* d_in, const int* in_sizes, int n_in,
                              void* d_out, int out_size, void* d_ws, size_t ws_size,
                              hipStream_t stream)
{
    const float* loc     = (const float*)d_in[0];
    const float* conf    = (const float*)d_in[1];
    const float* priors  = (const float*)d_in[2];
    const float* targets = (const float*)d_in[3];
    float* out = (float*)d_out;

    char* ws = (char*)d_ws;
    unsigned long long* bp_final = (unsigned long long*)ws;              // 5120 B
    unsigned long long* bovbt    = (unsigned long long*)(ws + 65536);    // 6288384 B
    float* pl = (float*)(ws + 65536 + 6291456);                          // KL_BLOCKS
    float* pn = pl + KL_BLOCKS;
    float* pc = pn + KL_BLOCKS;

    hipMemsetAsync(bp_final, 0, BB * TT * sizeof(unsigned long long), stream);
    k_bp<<<dim3(BP_SEGS, BB), 1024, 0, stream>>>(priors, targets, bp_final, bovbt);
    k_stream<<<KL_BLOCKS, 256, 0, stream>>>(conf, loc, priors, targets, bp_final,
                                            bovbt, pl, pn, pc);
    k_final<<<1, 256, 0, stream>>>(pl, pn, pc, out);
}

// Round 19
// 80.941 us; speedup vs baseline: 1.0962x; 1.0962x over previous
//
#include <hip/hip_runtime.h>

#define NCLS 81
#define BB 32
#define PP 24564
#define TT 20
#define BP_SEGS 8
#define BP_SEG 3072                       /* 8*3072 = 24576 >= 24564 */
#define KL_BLOCKS 1024                    /* 4 blocks/CU x 256 CU, exactly resident */
#define KL_ROWS 32                        /* rows per staged chunk */
#define KL_CHUNKS ((BB * PP) / KL_ROWS)   /* 786048/32 = 24564 exactly */
#define KL_F4 ((KL_ROWS * NCLS) / 4)      /* 648 float4 per chunk */

// async global->LDS DMA, 16B per lane; LDS dest = wave-uniform base + lane*16
#define GLOAD_LDS16(g, l)                                                  \
    __builtin_amdgcn_global_load_lds(                                      \
        (const __attribute__((address_space(1))) void*)(g),                \
        (__attribute__((address_space(3))) void*)(l), 16, 0, 0)

// Per-(b, prior-segment) block: 3 priors/thread in registers, loop 20 truths
// computing the EXACT f32 IoU quotient per (p,t). Two products per quotient:
//  (a) per-t argmax key (ov_bits<<32 | ~p) -> wave reduce -> 16-wave fold ->
//      bp_part[(b*TT+t)*8+seg]   (no atomics, no zero-init needed)
//  (b) per-prior best-truth key (ov_bits<<32 | 31-t) -> bovbt[b*PP+p]
__global__ __launch_bounds__(1024)
void k_bp(const float* __restrict__ priors,
          const float* __restrict__ targets,
          unsigned long long* __restrict__ bp_part,
          unsigned long long* __restrict__ bovbt)
{
    const int seg = blockIdx.x;   // 0..7
    const int b = blockIdx.y;

    __shared__ float trb[TT * 5];
    __shared__ unsigned long long wred[TT][16];
    if (threadIdx.x < TT * 5) trb[threadIdx.x] = targets[b * TT * 5 + threadIdx.x];
    __syncthreads();

    float X1[3], Y1[3], X2[3], Y2[3], pa[3];
    unsigned int pkey[3];
    bool ok[3];
    #pragma unroll
    for (int j = 0; j < 3; ++j) {
        int p = seg * BP_SEG + j * 1024 + threadIdx.x;
        ok[j] = p < PP;
        float4 pr = ok[j] ? ((const float4*)priors)[p] : make_float4(1.f, 1.f, 0.f, 0.f);
        float hw = __fmul_rn(pr.z, 0.5f), hh = __fmul_rn(pr.w, 0.5f);
        X1[j] = __fsub_rn(pr.x, hw); Y1[j] = __fsub_rn(pr.y, hh);
        X2[j] = __fadd_rn(pr.x, hw); Y2[j] = __fadd_rn(pr.y, hh);
        pa[j] = __fmul_rn(__fsub_rn(X2[j], X1[j]), __fsub_rn(Y2[j], Y1[j]));
        pkey[j] = 0xFFFFFFFFu - (unsigned)p;
    }

    const int wv = threadIdx.x >> 6;
    const int lane = threadIdx.x & 63;

    unsigned long long bkey[3] = {0ull, 0ull, 0ull};

    for (int t = 0; t < TT; ++t) {
        float tx1 = trb[t * 5 + 0], ty1 = trb[t * 5 + 1];
        float tx2 = trb[t * 5 + 2], ty2 = trb[t * 5 + 3];
        float ta = __fmul_rn(__fsub_rn(tx2, tx1), __fsub_rn(ty2, ty1));

        unsigned long long best = 0ull;
        #pragma unroll
        for (int j = 0; j < 3; ++j) {
            float lx = fmaxf(tx1, X1[j]), ly = fmaxf(ty1, Y1[j]);
            float rx = fminf(tx2, X2[j]), ry = fminf(ty2, Y2[j]);
            float w = fmaxf(__fsub_rn(rx, lx), 0.0f);
            float h = fmaxf(__fsub_rn(ry, ly), 0.0f);
            float inter = __fmul_rn(w, h);
            float denom = __fsub_rn(__fadd_rn(ta, pa[j]), inter);
            float ov = __fdiv_rn(inter, denom);   // exact numpy quotient bits
            unsigned long long ovhi = (unsigned long long)__float_as_uint(ov) << 32;
            unsigned long long key = ok[j] ? (ovhi | pkey[j]) : 0ull;
            if (key > best) best = key;
            unsigned long long rowk = ovhi | (unsigned long long)(31 - t);
            if (rowk > bkey[j]) bkey[j] = rowk;   // ties: smaller t (numpy first-max)
        }
        #pragma unroll
        for (int s = 32; s; s >>= 1) {
            unsigned long long o = __shfl_xor(best, s, 64);
            if (o > best) best = o;
        }
        if (lane == 0) wred[t][wv] = best;
    }

    #pragma unroll
    for (int j = 0; j < 3; ++j) {
        int p = seg * BP_SEG + j * 1024 + threadIdx.x;
        if (p < PP) bovbt[b * PP + p] = bkey[j];
    }

    __syncthreads();
    if (threadIdx.x < TT) {
        unsigned long long m = wred[threadIdx.x][0];
        #pragma unroll
        for (int w = 1; w < 16; ++w) if (wred[threadIdx.x][w] > m) m = wred[threadIdx.x][w];
        bp_part[(b * TT + threadIdx.x) * BP_SEGS + seg] = m;
    }
}

// Fold the 8 bp_part segments per (b,t) and write the forced-match override
// DIRECTLY into bovbt: bovbt[b*PP+p*] = pack(2.0f, 31-t), ascending t per b
// (one thread per b, sequential writes -> numpy scatter last-t-wins).
__global__ __launch_bounds__(64)
void k_fold(const unsigned long long* __restrict__ bp_part,
            unsigned long long* __restrict__ bovbt)
{
    int b = threadIdx.x;
    if (b < BB) {
        for (int t = 0; t < TT; ++t) {
            const unsigned long long* q = bp_part + (b * TT + t) * BP_SEGS;
            unsigned long long m = q[0];
            #pragma unroll
            for (int s = 1; s < BP_SEGS; ++s) if (q[s] > m) m = q[s];
            unsigned p = 0xFFFFFFFFu - (unsigned)(m & 0xFFFFFFFFull);
            bovbt[(size_t)b * PP + p] =
                (0x40000000ull << 32) | (unsigned long long)(31 - t);  // (2.0f, t)
        }
    }
}

// Streaming kernel, consolidated: proven 32-row DMA double-buffer + 8-lane
// exp-sum skeleton unchanged. Per chunk the leader only extracts {se, x[cc]}
// (~12 masked instr) into an LDS ring; every 8 chunks a 256-thread FULLY
// LANE-PARALLEL burst (1 row/thread, k_match's proven math) does encode/SL1/
// focal with coalesced bovbt/loc/priors reads. Forced override is pre-folded
// into bovbt (k_fold) -> no per-chunk scan/meta. trbAll loaded once.
__global__ __launch_bounds__(256, 4)
void k_stream(const float* __restrict__ conf,
              const float* __restrict__ loc,
              const float* __restrict__ priors,
              const float* __restrict__ targets,
              const unsigned long long* __restrict__ bovbt,
              float* __restrict__ pl, float* __restrict__ pn, float* __restrict__ pc)
{
    __shared__ float buf[2][KL_ROWS * NCLS];    // 20736 B
    __shared__ float trbAll[BB * TT * 5];       // 12800 B
    __shared__ float seb[256], xtb[256];        // 2048 B
    __shared__ int sidx[8];                     // 32 B
    __shared__ float red[256];                  // 1024 B  (total ~36.7 KB)

    const int tid = threadIdx.x;
    const int w = tid >> 6;
    const int lane = tid & 63;
    const int rl = tid >> 3;       // local row 0..31
    const int k = tid & 7;         // 8-group position within row
    const float4* conf4 = (const float4*)conf;

    auto stage = [&](int c, int bi) {
        const float4* src = conf4 + (size_t)c * KL_F4;
        float4* dst = (float4*)buf[bi];
        #pragma unroll
        for (int j = 0; j < 2; ++j) {
            int idx = j * 256 + w * 64 + lane;
            GLOAD_LDS16(src + idx, dst + idx);
        }
        if (tid < KL_F4 - 512) {
            int idx = 512 + tid;
            GLOAD_LDS16(src + idx, dst + idx);
        }
    };

    for (int i = tid; i < BB * TT * 5; i += 256) trbAll[i] = targets[i];

    const int c0 = blockIdx.x;
    stage(c0, 0);
    __syncthreads();

    float accL = 0.0f, accN = 0.0f, accC = 0.0f;
    int cur = 0, na = 0;

    // 256-thread lane-parallel deferred tail over n staged chunks
    auto burst = [&](int n) {
        int span = tid >> 5;                    // 0..7
        if (span < n) {
            int r = sidx[span] * KL_ROWS + (tid & 31);
            int b = r / PP;
            int p = r - b * PP;
            const float* trb = &trbAll[b * TT * 5];
            unsigned long long rk = bovbt[r];   // coalesced, L2-hot
            int bt = 31 - (int)(rk & 31ull);
            float bov = __uint_as_float((unsigned)(rk >> 32));
            int cc = (int)trb[bt * 5 + 4] + 1;
            if (bov < 0.5f) cc = -1;
            if (bov < 0.4f) cc = 0;
            int si = span * 32 + (tid & 31);
            if (cc > 0) {
                float4 pr = *(const float4*)(priors + p * 4);
                float mx1 = trb[bt * 5 + 0], my1 = trb[bt * 5 + 1];
                float mx2 = trb[bt * 5 + 2], my2 = trb[bt * 5 + 3];
                float cx = __fmul_rn(__fadd_rn(mx1, mx2), 0.5f);
                float cy = __fmul_rn(__fadd_rn(my1, my2), 0.5f);
                float gx = __fdiv_rn(__fsub_rn(cx, pr.x), __fmul_rn(0.1f, pr.z));
                float gy = __fdiv_rn(__fsub_rn(cy, pr.y), __fmul_rn(0.1f, pr.w));
                float gw = __fdiv_rn(logf(__fdiv_rn(__fsub_rn(mx2, mx1), pr.z)), 0.2f);
                float gh = __fdiv_rn(logf(__fdiv_rn(__fsub_rn(my2, my1), pr.w)), 0.2f);
                float4 ld = *(const float4*)(loc + (size_t)r * 4);
                float g0 = ld.x - gx, g1 = ld.y - gy, g2 = ld.z - gw, g3 = ld.w - gh;
                float a0 = fabsf(g0), a1 = fabsf(g1), a2 = fabsf(g2), a3 = fabsf(g3);
                accL += (a0 < 1.0f) ? 0.5f * g0 * g0 : (a0 - 0.5f);
                accL += (a1 < 1.0f) ? 0.5f * g1 * g1 : (a1 - 0.5f);
                accL += (a2 < 1.0f) ? 0.5f * g2 * g2 : (a2 - 0.5f);
                accL += (a3 < 1.0f) ? 0.5f * g3 * g3 : (a3 - 0.5f);
                accN += 1.0f;
            }
            if (cc >= 0) {
                float logpt = xtb[si] - __logf(seb[si]);
                float pt = __expf(logpt);
                float at = (cc > 0) ? 0.25f : 0.75f;
                float om = 1.0f - pt;
                accC -= at * om * om * logpt;
            }
        }
        __syncthreads();   // protect seb/xtb/sidx ring before reuse
    };

    for (int c = c0; c < KL_CHUNKS; c += KL_BLOCKS) {
        int cn = c + KL_BLOCKS;
        if (cn < KL_CHUNKS) stage(cn, cur ^ 1);

        int r = c * KL_ROWS + rl;
        unsigned long long rk = (k == 0) ? bovbt[r] : 0ull;   // early issue

        // ---- exp-sum phase (8 threads/row) ----
        const float* row = buf[cur] + rl * NCLS;
        float se = 0.0f;
        #pragma unroll
        for (int i = 0; i < 10; ++i) se += __expf(row[k * 10 + i]);
        if (k == 0) se += __expf(row[80]);
        se += __shfl_xor(se, 1, 8);
        se += __shfl_xor(se, 2, 8);
        se += __shfl_xor(se, 4, 8);

        // ---- leader: extract {se, x[cc]} only (tail deferred to burst) ----
        if (k == 0) {
            int b = r / PP;
            int bt = 31 - (int)(rk & 31ull);
            float bov = __uint_as_float((unsigned)(rk >> 32));
            int cc = (int)trbAll[b * TT * 5 + bt * 5 + 4] + 1;
            if (bov < 0.5f) cc = -1;
            if (bov < 0.4f) cc = 0;
            seb[na * 32 + rl] = se;
            xtb[na * 32 + rl] = row[cc < 0 ? 0 : cc];
        }
        if (tid == 0) sidx[na] = c;
        __syncthreads();   // dbuf safety + seb/xtb/sidx visible
        ++na;
        if (na == 8) { burst(8); na = 0; }
        cur ^= 1;
    }
    if (na > 0) burst(na);

    // ---- block reduction ----
    red[tid] = accL;
    __syncthreads();
    for (int s = 128; s; s >>= 1) {
        if (tid < s) red[tid] += red[tid + s];
        __syncthreads();
    }
    if (tid == 0) pl[blockIdx.x] = red[0];
    __syncthreads();

    red[tid] = accN;
    __syncthreads();
    for (int s = 128; s; s >>= 1) {
        if (tid < s) red[tid] += red[tid + s];
        __syncthreads();
    }
    if (tid == 0) pn[blockIdx.x] = red[0];
    __syncthreads();

    red[tid] = accC;
    __syncthreads();
    for (int s = 128; s; s >>= 1) {
        if (tid < s) red[tid] += red[tid + s];
        __syncthreads();
    }
    if (tid == 0) pc[blockIdx.x] = red[0];
}

__global__ __launch_bounds__(256)
void k_final(const float* __restrict__ pl, const float* __restrict__ pn,
             const float* __restrict__ pc, float* __restrict__ out)
{
    __shared__ float sl[256], sc[256], sn[256];
    float L = 0.0f, C = 0.0f, N = 0.0f;
    for (int i = threadIdx.x; i < KL_BLOCKS; i += 256) {
        L += pl[i]; N += pn[i]; C += pc[i];
    }
    sl[threadIdx.x] = L; sc[threadIdx.x] = C; sn[threadIdx.x] = N;
    __syncthreads();
    for (int s = 128; s; s >>= 1) {
        if (threadIdx.x < s) {
            sl[threadIdx.x] += sl[threadIdx.x + s];
            sc[threadIdx.x] += sc[threadIdx.x + s];
            sn[threadIdx.x] += sn[threadIdx.x + s];
        }
        __syncthreads();
    }
    if (threadIdx.x == 0) {
        out[0] = sl[0] / sn[0];
        out[1] = sc[0] / sn[0];
    }
}

extern "C" void kernel_launch(void* const* d_in, const int* in_sizes, int n_in,
                              void* d_out, int out_size, void* d_ws, size_t ws_size,
                              hipStream_t stream)
{
    const float* loc     = (const float*)d_in[0];
    const float* conf    = (const float*)d_in[1];
    const float* priors  = (const float*)d_in[2];
    const float* targets = (const float*)d_in[3];
    float* out = (float*)d_out;

    char* ws = (char*)d_ws;
    unsigned long long* bp_part = (unsigned long long*)ws;               // 40960 B
    unsigned long long* bovbt   = (unsigned long long*)(ws + 65536);     // 6288384 B
    float* pl = (float*)(ws + 65536 + 6291456);                          // KL_BLOCKS
    float* pn = pl + KL_BLOCKS;
    float* pc = pn + KL_BLOCKS;

    k_bp<<<dim3(BP_SEGS, BB), 1024, 0, stream>>>(priors, targets, bp_part, bovbt);
    k_fold<<<1, 64, 0, stream>>>(bp_part, bovbt);
    k_stream<<<KL_BLOCKS, 256, 0, stream>>>(conf, loc, priors, targets, bovbt,
                                            pl, pn, pc);
    k_final<<<1, 256, 0, stream>>>(pl, pn, pc, out);
}